// Round 2
// baseline (11851.731 us; speedup 1.0000x reference)
//
#include <hip/hip_runtime.h>
#include <hip/hip_bf16.h>
#include <cstddef>

// ---------------- problem constants ----------------
constexpr int cB = 8, cL = 12, cN = 207, cD = 512, cH = 8, cF = 2048;
constexpr int cO = 12, cNG = 3;
constexpr int cT  = cL * cN;          // 2484
constexpr int cBT = cB * cT;          // 19872
constexpr int cE  = cD / cH;          // 64
constexpr int cCCAT = cD * (cNG + 1) * 2 + cD;  // 4608
constexpr size_t SZ = (size_t)cBT * cD;         // 10,174,464
constexpr int NN = cN * cN;           // 42849

// ---------------- dynamic-dtype helpers ----------------
__device__ __forceinline__ float ldin(const void* p, size_t i, int bf) {
    return bf ? __bfloat162float(((const __hip_bfloat16*)p)[i])
              : ((const float*)p)[i];
}
__device__ __forceinline__ void stout(void* p, size_t i, float v, int bf) {
    if (bf) ((__hip_bfloat16*)p)[i] = __float2bfloat16(v);
    else    ((float*)p)[i] = v;
}

__device__ __forceinline__ float gelu_f(float x) {
    float x3 = x * x * x;
    return 0.5f * x * (1.f + tanhf(0.7978845608028654f * (x + 0.044715f * x3)));
}

// ---------------- dtype detection ----------------
// Read first 1024 half-words of x as bf16. True-bf16 N(0,1) data: max < ~6.
// fp32-backed data: low half-words carry random exponents -> max >> 1e3.
__global__ void detect_kernel(const void* __restrict__ x, int* __restrict__ flag) {
    __shared__ float red[4];
    int t = threadIdx.x;
    float m = 0.f;
    for (int i = t; i < 1024; i += 256) {
        float v = __bfloat162float(((const __hip_bfloat16*)x)[i]);
        if (v != v) v = 1e30f;
        m = fmaxf(m, fabsf(v));
    }
#pragma unroll
    for (int off = 32; off; off >>= 1) m = fmaxf(m, __shfl_down(m, off));
    if ((t & 63) == 0) red[t >> 6] = m;
    __syncthreads();
    if (t == 0) {
        float mm = fmaxf(fmaxf(red[0], red[1]), fmaxf(red[2], red[3]));
        flag[0] = (mm < 1e3f) ? 1 : 0;   // 1 = bf16 inputs, 0 = fp32 inputs
    }
}

// ---------------- generic tiled GEMM (fp32 accum, dynamic dtypes) ----------------
// C[bz](MxN) = A[bz](MxK) @ B[bz](KxN)        (TRB=false)
//           or A[bz](MxK) @ B[bz](NxK)^T      (TRB=true)
// element offsets: A idx += aoff0 + batchA*sA ; B idx += boff0 + batchB*sB
template <bool ADYN, bool BDYN, bool TRB, int BIAS, int ACT, bool ACC>
__global__ __launch_bounds__(256) void gemm_kernel(
    const void* __restrict__ Ab, const void* __restrict__ Bb, float* __restrict__ Cb,
    const void* __restrict__ bias, const int* __restrict__ flagp,
    int M, int N, int K, int lda, int ldb, int ldc,
    long sA, long sB, long sC, int modA, int modB,
    size_t aoff0, size_t boff0, size_t biasoff)
{
    constexpr int BM = 64, BN = 64, BK = 16;
    int bf = (ADYN || BDYN) ? *flagp : 0;
    const int abf = ADYN ? bf : 0;
    const int bbf = BDYN ? bf : 0;

    int bz = blockIdx.z;
    size_t aoff = aoff0 + (size_t)(modA ? (bz % modA) : bz) * sA;
    size_t boff = boff0 + (size_t)(modB ? (bz % modB) : bz) * sB;
    float* C = Cb + (size_t)bz * sC;

    int m0 = blockIdx.y * BM;
    int n0 = blockIdx.x * BN;
    int tid = threadIdx.x;
    int tx = tid & 15, ty = tid >> 4;

    __shared__ float As[BK][BM];
    __shared__ float Bs[BK][BN];

    float acc[4][4] = {};

    for (int k0 = 0; k0 < K; k0 += BK) {
#pragma unroll
        for (int i = 0; i < 4; ++i) {
            int idx = tid + i * 256;
            int k = idx & 15, m = idx >> 4;
            int gm = m0 + m, gk = k0 + k;
            float v = 0.f;
            if (gm < M && gk < K) v = ldin(Ab, aoff + (size_t)gm * lda + gk, abf);
            As[k][m] = v;
        }
#pragma unroll
        for (int i = 0; i < 4; ++i) {
            int idx = tid + i * 256;
            if (!TRB) {
                int n = idx & 63, k = idx >> 6;
                int gn = n0 + n, gk = k0 + k;
                float v = 0.f;
                if (gn < N && gk < K) v = ldin(Bb, boff + (size_t)gk * ldb + gn, bbf);
                Bs[k][n] = v;
            } else {
                int k = idx & 15, n = idx >> 4;
                int gn = n0 + n, gk = k0 + k;
                float v = 0.f;
                if (gn < N && gk < K) v = ldin(Bb, boff + (size_t)gn * ldb + gk, bbf);
                Bs[k][n] = v;
            }
        }
        __syncthreads();
#pragma unroll
        for (int k = 0; k < BK; ++k) {
            float a[4], bb[4];
#pragma unroll
            for (int i = 0; i < 4; ++i) a[i] = As[k][ty * 4 + i];
#pragma unroll
            for (int j = 0; j < 4; ++j) bb[j] = Bs[k][tx * 4 + j];
#pragma unroll
            for (int i = 0; i < 4; ++i)
#pragma unroll
                for (int j = 0; j < 4; ++j) acc[i][j] += a[i] * bb[j];
        }
        __syncthreads();
    }

#pragma unroll
    for (int i = 0; i < 4; ++i) {
        int gm = m0 + ty * 4 + i;
        if (gm >= M) continue;
#pragma unroll
        for (int j = 0; j < 4; ++j) {
            int gn = n0 + tx * 4 + j;
            if (gn >= N) continue;
            float v = acc[i][j];
            if (BIAS == 1) v += ldin(bias, biasoff + gn, bbf);
            if (BIAS == 2) v += ldin(bias, biasoff + gm, bbf);
            if (ACT == 1) v = gelu_f(v);
            size_t ci = (size_t)gm * ldc + gn;
            if (ACC) C[ci] += v; else C[ci] = v;
        }
    }
}

// ---------------- elementwise / attention kernels (fp32 internal) ----------------
__global__ void eluplus1_kernel(float* __restrict__ p, size_t n) {
    size_t i = (size_t)blockIdx.x * 256 + threadIdx.x;
    if (i < n) { float v = p[i]; p[i] = v > 0.f ? v + 1.f : expf(v); }
}

__global__ void zerof_kernel(float* __restrict__ p, size_t n) {
    size_t i = (size_t)blockIdx.x * 256 + threadIdx.x;
    if (i < n) p[i] = 0.f;
}

// kv[b,h,e,d] = sum_t kf[b,t,h,e]*v[b,t,h,d] ; ksum[b,h,e] = sum_t kf
__global__ __launch_bounds__(256) void kv_ksum_kernel(
    const float* __restrict__ Kf, const float* __restrict__ V,
    float* __restrict__ kv, float* __restrict__ ksum)
{
    int bh = blockIdx.x;
    int b = bh / cH, h = bh % cH;
    __shared__ float ks[32][64];
    __shared__ float vs[32][64];
    int tid = threadIdx.x;
    int e = tid >> 2;
    int dg = tid & 3;
    float acc[16] = {};
    float ksacc = 0.f;
    for (int t0 = 0; t0 < cT; t0 += 32) {
        for (int i = tid; i < 32 * 64; i += 256) {
            int tt = i >> 6, ee = i & 63;
            int t = t0 + tt;
            float kk = 0.f, vv = 0.f;
            if (t < cT) {
                size_t off = ((size_t)(b * cT + t)) * cD + h * cE;
                kk = Kf[off + ee];
                vv = V[off + ee];
            }
            ks[tt][ee] = kk;
            vs[tt][ee] = vv;
        }
        __syncthreads();
        for (int tt = 0; tt < 32; ++tt) {
            float kf = ks[tt][e];
            if (dg == 0) ksacc += kf;
#pragma unroll
            for (int j = 0; j < 16; ++j) acc[j] += kf * vs[tt][dg * 16 + j];
        }
        __syncthreads();
    }
    size_t base = ((size_t)bh * cE + e) * cE;
#pragma unroll
    for (int j = 0; j < 16; ++j) kv[base + dg * 16 + j] = acc[j];
    if (dg == 0) ksum[bh * cE + e] = ksacc;
}

// O[b,t,h,d] = (sum_e qf[e]*kv[b,h,e,d]) / (sum_e qf[e]*ksum[b,h,e] + eps)
// Safe with O == Qf (each block owns its 64-wide segment exclusively).
__global__ __launch_bounds__(64) void attn_o_kernel(
    const float* __restrict__ Qf, const float* __restrict__ kv,
    const float* __restrict__ ksum, float* __restrict__ O)
{
    int g = blockIdx.x;
    int h = g % cH;
    int bt = g / cH;
    int b = bt / cT;
    int bh = b * cH + h;
    int d = threadIdx.x;
    size_t qoff = (size_t)bt * cD + h * cE;
    __shared__ float qs[64];
    float qv = Qf[qoff + d];
    qs[d] = qv;
    float p = qv * ksum[bh * cE + d];
#pragma unroll
    for (int s = 32; s; s >>= 1) p += __shfl_down(p, s);
    float denom = __shfl(p, 0);
    __syncthreads();
    float z = 1.f / (denom + 1e-6f);
    const float* kvp = kv + (size_t)bh * cE * cE;
    float acc = 0.f;
#pragma unroll 8
    for (int e = 0; e < 64; ++e) acc += qs[e] * kvp[e * 64 + d];
    O[qoff + d] = acc * z;
}

// out = LN(a + b) * gamma + beta  (row len 512; safe with out==a)
template <bool ADYN, bool ODYN>
__global__ __launch_bounds__(256) void add_ln_kernel(
    const void* __restrict__ a, const float* __restrict__ b,
    const void* __restrict__ g, const void* __restrict__ be,
    void* __restrict__ out, const int* __restrict__ flagp,
    size_t goff, size_t ooff)
{
    int bf = *flagp;
    const int abf = ADYN ? bf : 0;
    const int obf = ODYN ? bf : 0;
    int row = blockIdx.x;
    size_t base = (size_t)row * cD;
    int t = threadIdx.x;
    float x0 = ldin(a, base + t, abf)       + b[base + t];
    float x1 = ldin(a, base + t + 256, abf) + b[base + t + 256];
    float s1 = x0 + x1, s2 = x0 * x0 + x1 * x1;
#pragma unroll
    for (int off = 32; off; off >>= 1) { s1 += __shfl_down(s1, off); s2 += __shfl_down(s2, off); }
    __shared__ float r1[4], r2[4];
    int w = t >> 6;
    if ((t & 63) == 0) { r1[w] = s1; r2[w] = s2; }
    __syncthreads();
    float S1 = r1[0] + r1[1] + r1[2] + r1[3];
    float S2 = r2[0] + r2[1] + r2[2] + r2[3];
    float mean = S1 * (1.f / cD);
    float var = S2 * (1.f / cD) - mean * mean;
    float inv = rsqrtf(var + 1e-5f);
    stout(out, ooff + base + t,       (x0 - mean) * inv * ldin(g, goff + t, bf)       + ldin(be, goff + t, bf),       obf);
    stout(out, ooff + base + t + 256, (x1 - mean) * inv * ldin(g, goff + t + 256, bf) + ldin(be, goff + t + 256, bf), obf);
}

// XT[b,o,n,d] = sum_l tt_w[o,l]*t_out[b,l,n,d] + tt_b[o]
__global__ void tout2_kernel(const float* __restrict__ tout, const void* __restrict__ ttw,
                             const void* __restrict__ ttb, float* __restrict__ XT,
                             const int* __restrict__ flagp)
{
    int bf = *flagp;
    size_t idx = (size_t)blockIdx.x * 256 + threadIdx.x;
    if (idx >= SZ) return;
    int d = idx & (cD - 1);
    size_t r = idx >> 9;
    int n = (int)(r % cN);
    size_t r2 = r / cN;
    int o = (int)(r2 % cO);
    int b = (int)(r2 / cO);
    float acc = ldin(ttb, o, bf);
    size_t base = ((size_t)b * cT + n) * cD + d;
#pragma unroll
    for (int l = 0; l < cL; ++l)
        acc += ldin(ttw, o * cL + l, bf) * tout[base + (size_t)l * cN * cD];
    XT[idx] = acc;
}

// At3[s][m][n] = adj[n,m,s]
__global__ void extract_adjT_kernel(const void* __restrict__ adj, float* __restrict__ At3,
                                    const int* __restrict__ flagp)
{
    int bf = *flagp;
    int idx = blockIdx.x * 256 + threadIdx.x;
    if (idx >= cNG * NN) return;
    int s = idx / NN;
    int rem = idx - s * NN;
    int m = rem / cN;
    int n = rem - m * cN;
    At3[idx] = ldin(adj, (size_t)(n * cN + m) * cNG + s, bf);
}

// dts[b,o,n,d] = (g_T + gcn_b[o,d]) * bn_g[o,d] + bn_b[o,d]
__global__ void dts_kernel(const float* __restrict__ g, const void* __restrict__ gb,
                           const void* __restrict__ bng, const void* __restrict__ bnb,
                           void* __restrict__ out, const int* __restrict__ flagp)
{
    int bf = *flagp;
    size_t idx = (size_t)blockIdx.x * 256 + threadIdx.x;
    if (idx >= SZ) return;
    int d = idx & (cD - 1);
    size_t r = idx >> 9;
    int o = (int)((r / cN) % cO);
    int od = o * cD + d;
    float v = (g[idx] + ldin(gb, od, bf)) * ldin(bng, od, bf) + ldin(bnb, od, bf);
    stout(out, idx, v, bf);
}

// ---------------- host-side helpers ----------------
static inline dim3 ggrid(int M, int N, int batch) {
    return dim3((N + 63) / 64, (M + 63) / 64, batch);
}

template <bool ADYN>
static void proj_t(const void* A, const void* w, size_t woff, const void* b, size_t boff,
                   float* C, const int* fl, hipStream_t s) {
    gemm_kernel<ADYN, true, false, 1, 0, false><<<ggrid(cBT, cD, 1), 256, 0, s>>>(
        A, w, C, b, fl, cBT, cD, cD, cD, cD, cD, 0L, 0L, 0L, 1, 1, 0, woff, boff);
}

// R0 = 3*SZ scratch. Result lands at R0+SZ.
template <bool QDYN, bool KDYN>
static void run_attn(const void* xq, const void* xkv, const void* w, const void* b,
                     float* R0, float* kvb, float* ksb, const int* fl, hipStream_t s)
{
    float* Q = R0;
    float* K = R0 + SZ;
    float* V = R0 + 2 * SZ;
    const size_t DD = (size_t)cD * cD;
    proj_t<QDYN>(xq,  w, 0,      b, 0,      Q, fl, s);
    proj_t<KDYN>(xkv, w, DD,     b, cD,     K, fl, s);
    proj_t<KDYN>(xkv, w, 2 * DD, b, 2 * cD, V, fl, s);
    size_t ne = 2 * SZ;
    eluplus1_kernel<<<(int)((ne + 255) / 256), 256, 0, s>>>(Q, ne);
    kv_ksum_kernel<<<cB * cH, 256, 0, s>>>(K, V, kvb, ksb);
    attn_o_kernel<<<cBT * cH, 64, 0, s>>>(Q, kvb, ksb, Q);          // O in-place over Q
    proj_t<false>(Q, w, 3 * DD, b, 3 * cD, K, fl, s);               // out -> K buffer
}

// mid = 2*SZ scratch; split rows in halves to bound mid size.
static void run_ffn(const float* inp, const void* w1, const void* b1,
                    const void* w2, const void* b2, float* mid, float* outp,
                    const int* fl, hipStream_t s)
{
    const int MH = cBT / 2;  // 9936
    for (int h = 0; h < 2; ++h) {
        const float* ip = inp + (size_t)h * MH * cD;
        float* op = outp + (size_t)h * MH * cD;
        gemm_kernel<false, true, false, 1, 1, false><<<ggrid(MH, cF, 1), 256, 0, s>>>(
            ip, w1, mid, b1, fl, MH, cF, cD, cD, cF, cF, 0L, 0L, 0L, 1, 1, 0, 0, 0);
        gemm_kernel<false, true, false, 1, 0, false><<<ggrid(MH, cD, 1), 256, 0, s>>>(
            mid, w2, op, b2, fl, MH, cD, cF, cF, cD, cD, 0L, 0L, 0L, 1, 1, 0, 0, 0);
    }
}

// g_T[bz] += Feat[bz] @ gcn_w[o, :, f*512:(f+1)*512]^T
static void launch_accum(const float* Feat, const void* gw, float* g, int f,
                         const int* fl, hipStream_t s) {
    gemm_kernel<false, true, true, 0, 0, true><<<ggrid(cN, cD, cB * cO), 256, 0, s>>>(
        Feat, gw, g, (const void*)nullptr, fl,
        cN, cD, cD, cD, cCCAT, cD,
        (long)cN * cD, (long)cD * cCCAT, (long)cN * cD, 0, cO,
        0, (size_t)f * cD, 0);
}

static void launch_featmul_fixedA(const float* At, const float* Fin, float* Fout,
                                  const int* fl, hipStream_t s) {
    gemm_kernel<false, false, false, 0, 0, false><<<ggrid(cN, cD, cB * cO), 256, 0, s>>>(
        At, Fin, Fout, (const void*)nullptr, fl,
        cN, cD, cN, cN, cD, cD,
        0L, (long)cN * cD, (long)cN * cD, 1, 0, 0, 0, 0);
}

static void launch_featmul_batchA(const float* Aad, const float* Fin, float* Fout,
                                  const int* fl, hipStream_t s) {
    gemm_kernel<false, false, false, 0, 0, false><<<ggrid(cN, cD, cB * cO), 256, 0, s>>>(
        Aad, Fin, Fout, (const void*)nullptr, fl,
        cN, cD, cN, cN, cD, cD,
        (long)NN, (long)cN * cD, (long)cN * cD, 0, 0, 0, 0, 0);
}

// ---------------- entry point ----------------
extern "C" void kernel_launch(void* const* d_in, const int* in_sizes, int n_in,
                              void* d_out, int out_size, void* d_ws, size_t ws_size,
                              hipStream_t stream)
{
    const void* x    = d_in[0];
    const void* st   = d_in[1];
    const void* adj  = d_in[3];
    const void* eqw  = d_in[4];
    const void* eqb  = d_in[5];
    const void* ew1  = d_in[6];
    const void* eb1  = d_in[7];
    const void* ew2  = d_in[8];
    const void* eb2  = d_in[9];
    const void* elng = d_in[10];
    const void* elnb = d_in[11];
    const void* dsw  = d_in[12];
    const void* dsb  = d_in[13];
    const void* dcw  = d_in[14];
    const void* dcb  = d_in[15];
    const void* dw1  = d_in[16];
    const void* db1  = d_in[17];
    const void* dw2  = d_in[18];
    const void* db2  = d_in[19];
    const void* dlng = d_in[20];
    const void* dlnb = d_in[21];
    const void* ttw  = d_in[22];
    const void* ttb  = d_in[23];
    const void* tsw  = d_in[24];
    const void* tsb  = d_in[25];
    const void* gw   = d_in[26];
    const void* gb   = d_in[27];
    const void* bng  = d_in[28];
    const void* bnb  = d_in[29];

    float* ws = (float*)d_ws;
    float* R0 = ws;            // 3*SZ: QKV / FFN-mid(2SZ) / graph Fp,Fq,G
    float* R1 = ws + 3 * SZ;   // y -> t_out (mem)
    float* R2 = ws + 4 * SZ;   // ffn-out / q1 -> q2 / X_T
    float* R3 = ws + 5 * SZ;   // kvb+ksb | dec-ffn-out | AadT+At3
    int* flagp = (int*)(ws + 6 * SZ);

    float* kvb  = R3;
    float* ksb  = R3 + (size_t)cB * cH * cE * cE;
    float* AadT = R3;
    float* At3  = R3 + (size_t)cB * cO * NN;

    detect_kernel<<<1, 256, 0, stream>>>(x, flagp);

    // ===== encoder =====
    run_attn<true, true>(x, x, eqw, eqb, R0, kvb, ksb, flagp, stream);
    add_ln_kernel<true, false><<<cBT, 256, 0, stream>>>(x, R0 + SZ, elng, elnb, R1, flagp, 0, 0);      // y
    run_ffn(R1, ew1, eb1, ew2, eb2, R0, R2, flagp, stream);
    add_ln_kernel<false, false><<<cBT, 256, 0, stream>>>(R1, R2, elng, elnb, R1, flagp, cD, 0);        // t_out (in-place)

    // ===== decoder self-attn =====
    run_attn<true, true>(st, st, dsw, dsb, R0, kvb, ksb, flagp, stream);
    add_ln_kernel<true, false><<<cBT, 256, 0, stream>>>(st, R0 + SZ, dlng, dlnb, R2, flagp, 0, 0);     // q1

    // ===== decoder cross-attn =====
    run_attn<false, false>(R2, R1, dcw, dcb, R0, kvb, ksb, flagp, stream);
    add_ln_kernel<false, false><<<cBT, 256, 0, stream>>>(R2, R0 + SZ, dlng, dlnb, R2, flagp, cD, 0);   // q2 (in-place)

    // ===== decoder FFN + s_out (output element offset SZ, dyn dtype) =====
    run_ffn(R2, dw1, db1, dw2, db2, R0, R3, flagp, stream);
    add_ln_kernel<false, true><<<cBT, 256, 0, stream>>>(R2, R3, dlng, dlnb, d_out, flagp, 2 * cD, SZ);

    // ===== temporal projection: X_T[b,o,n,d] =====
    tout2_kernel<<<(int)((SZ + 255) / 256), 256, 0, stream>>>(R1, ttw, ttb, R2, flagp);

    // ===== adaptive adjacency (transposed): AadT[b,o,m,n] = ts_w · s_out^T + ts_b =====
    gemm_kernel<true, true, true, 2, 0, false><<<ggrid(cN, cN, cB * cO), 256, 0, stream>>>(
        tsw, d_out, AadT, tsb, flagp, cN, cN, cD, cD, cD, cN,
        0L, (long)cN * cD, (long)NN, 1, 0, 0, SZ, 0);

    extract_adjT_kernel<<<(cNG * NN + 255) / 256, 256, 0, stream>>>(adj, At3, flagp);

    // ===== graph diffusion + GCN accumulation =====
    float* Fp = R0;
    float* Fq = R0 + SZ;
    float* G  = R0 + 2 * SZ;
    zerof_kernel<<<(int)((SZ + 255) / 256), 256, 0, stream>>>(G, SZ);

    launch_accum(R2, gw, G, 0, flagp, stream);                    // f=0: xg
    for (int s = 0; s < cNG; ++s) {
        const float* At = At3 + (size_t)s * NN;
        launch_featmul_fixedA(At, R2, Fp, flagp, stream);
        launch_accum(Fp, gw, G, 2 * s + 1, flagp, stream);
        launch_featmul_fixedA(At, Fp, Fq, flagp, stream);
        launch_accum(Fq, gw, G, 2 * s + 2, flagp, stream);
    }
    launch_featmul_batchA(AadT, R2, Fp, flagp, stream);
    launch_accum(Fp, gw, G, 7, flagp, stream);
    launch_featmul_batchA(AadT, Fp, Fq, flagp, stream);
    launch_accum(Fq, gw, G, 8, flagp, stream);

    // ===== epilogue: BN + write dts =====
    dts_kernel<<<(int)((SZ + 255) / 256), 256, 0, stream>>>(G, gb, bng, bnb, d_out, flagp);
}

// Round 3
// 3137.995 us; speedup vs baseline: 3.7768x; 3.7768x over previous
//
#include <hip/hip_runtime.h>
#include <hip/hip_bf16.h>
#include <cstddef>

using bf16 = __hip_bfloat16;
typedef short s8v __attribute__((ext_vector_type(8)));
typedef __bf16 b8v __attribute__((ext_vector_type(8)));
typedef float f4v __attribute__((ext_vector_type(4)));

// ---------------- problem constants ----------------
constexpr int cB = 8, cL = 12, cN = 207, cD = 512, cH = 8, cF = 2048;
constexpr int cO = 12, cNG = 3;
constexpr int cT  = cL * cN;          // 2484
constexpr int cBT = cB * cT;          // 19872
constexpr int cE  = cD / cH;          // 64
constexpr size_t SZ = (size_t)cBT * cD;   // 10,174,464
constexpr int NNP = cN * 208;         // padded adjacency row stride region (207x208)
constexpr long DD = (long)cD * cD;    // 262144

// ---------------- helpers ----------------
__device__ __forceinline__ float tofl(bf16 v) { return __bfloat162float(v); }
__device__ __forceinline__ bf16 f2b(float v) { return __float2bfloat16(v); }
__device__ __forceinline__ float ldin(const void* p, size_t i, int bf) {
    return bf ? __bfloat162float(((const bf16*)p)[i]) : ((const float*)p)[i];
}
__device__ __forceinline__ void stout(void* p, size_t i, float v, int bf) {
    if (bf) ((bf16*)p)[i] = f2b(v);
    else    ((float*)p)[i] = v;
}
__device__ __forceinline__ float gelu_f(float x) {
    float x3 = x * x * x;
    return 0.5f * x * (1.f + tanhf(0.7978845608028654f * (x + 0.044715f * x3)));
}

// ---------------- dtype detection ----------------
__global__ void detect_kernel(const void* __restrict__ x, int* __restrict__ flag) {
    __shared__ float red[4];
    int t = threadIdx.x;
    float m = 0.f;
    for (int i = t; i < 1024; i += 256) {
        float v = __bfloat162float(((const bf16*)x)[i]);
        if (v != v) v = 1e30f;
        m = fmaxf(m, fabsf(v));
    }
#pragma unroll
    for (int off = 32; off; off >>= 1) m = fmaxf(m, __shfl_down(m, off));
    if ((t & 63) == 0) red[t >> 6] = m;
    __syncthreads();
    if (t == 0) {
        float mm = fmaxf(fmaxf(red[0], red[1]), fmaxf(red[2], red[3]));
        flag[0] = (mm < 1e3f) ? 1 : 0;
    }
}

// ---------------- convert kernels ----------------
__global__ void cvt_copy(bf16* __restrict__ dst, const void* __restrict__ src,
                         const int* __restrict__ fl, size_t n, size_t soff) {
    int bf = *fl;
#pragma unroll
    for (int j = 0; j < 4; ++j) {
        size_t i = (size_t)blockIdx.x * 1024 + (size_t)j * 256 + threadIdx.x;
        if (i < n) dst[i] = f2b(ldin(src, soff + i, bf));
    }
}
// dst[n*K + k] = src[soff + k*N + n]
__global__ void cvt_tr(bf16* __restrict__ dst, const void* __restrict__ src,
                       const int* __restrict__ fl, int K, int N, size_t soff) {
    int bf = *fl;
    size_t idx = (size_t)blockIdx.x * 256 + threadIdx.x;
    if (idx >= (size_t)K * N) return;
    int n = (int)(idx / K), k = (int)(idx % K);
    dst[idx] = f2b(ldin(src, soff + (size_t)k * N + n, bf));
}

// ---------------- MFMA GEMM ----------------
// C[bz](MxN) = A[bz](MxK,row) @ B'  ;  TRB=true: B row-major NxK; TRB=false: B row-major KxN
// OUT: 0=bf16 store, 1=f32 store, 2=f32 +=
template <bool TRB, int BIAS, int ACT, int OUT>
__global__ __launch_bounds__(256) void mgemm(
    const bf16* __restrict__ Ab, const bf16* __restrict__ Bb, void* __restrict__ Cb,
    const bf16* __restrict__ bias,
    int M, int N, int K, int lda, int ldb, int ldc,
    long sA, long sB, long sC, int modA, int modB, long aoff0, long boff0)
{
    int bz = blockIdx.z;
    const bf16* A = Ab + aoff0 + (size_t)(modA ? (bz % modA) : bz) * sA;
    const bf16* B = Bb + boff0 + (size_t)(modB ? (bz % modB) : bz) * sB;
    size_t coff = (size_t)bz * sC;

    int m0 = blockIdx.y * 128, n0 = blockIdx.x * 128;
    int tid = threadIdx.x;
    int lane = tid & 63, w = tid >> 6;
    int wm = (w & 1) * 64, wn = (w >> 1) * 64;
    int l16 = lane & 15, quad = lane >> 4;

    __shared__ short Asl[128 * 40];
    __shared__ short Bsl[128 * 40];

    f4v acc[4][4] = {};

    for (int k0 = 0; k0 < K; k0 += 32) {
        // ---- stage A: rows m, K-contiguous ----
        for (int g = tid; g < 512; g += 256) {
            int r = g >> 2, kg = (g & 3) << 3;
            int gr = m0 + r, gk = k0 + kg;
            s8v val = {0, 0, 0, 0, 0, 0, 0, 0};
            if (gr < M) {
                const short* src = (const short*)A + (size_t)gr * lda + gk;
                if (gk + 8 <= K) val = *(const s8v*)src;
                else {
#pragma unroll
                    for (int j = 0; j < 8; ++j) if (gk + j < K) val[j] = src[j];
                }
            }
            *(s8v*)&Asl[r * 40 + kg] = val;
        }
        // ---- stage B ----
        if (TRB) {
            for (int g = tid; g < 512; g += 256) {
                int r = g >> 2, kg = (g & 3) << 3;
                int gr = n0 + r, gk = k0 + kg;
                s8v val = {0, 0, 0, 0, 0, 0, 0, 0};
                if (gr < N) {
                    const short* src = (const short*)B + (size_t)gr * ldb + gk;
                    if (gk + 8 <= K) val = *(const s8v*)src;
                    else {
#pragma unroll
                        for (int j = 0; j < 8; ++j) if (gk + j < K) val[j] = src[j];
                    }
                }
                *(s8v*)&Bsl[r * 40 + kg] = val;
            }
        } else {
            for (int g = tid; g < 512; g += 256) {
                int kr = g >> 4, ng = (g & 15) << 3;
                int gk = k0 + kr, gn = n0 + ng;
                s8v val = {0, 0, 0, 0, 0, 0, 0, 0};
                if (gk < K) {
                    const short* src = (const short*)B + (size_t)gk * ldb + gn;
                    if (gn + 8 <= N) val = *(const s8v*)src;
                    else {
#pragma unroll
                        for (int j = 0; j < 8; ++j) if (gn + j < N) val[j] = src[j];
                    }
                }
#pragma unroll
                for (int j = 0; j < 8; ++j) Bsl[(ng + j) * 40 + kr] = val[j];
            }
        }
        __syncthreads();
        // ---- compute ----
        b8v af[4], bfr[4];
#pragma unroll
        for (int mi = 0; mi < 4; ++mi)
            af[mi] = *(const b8v*)&Asl[(wm + mi * 16 + l16) * 40 + quad * 8];
#pragma unroll
        for (int ni = 0; ni < 4; ++ni)
            bfr[ni] = *(const b8v*)&Bsl[(wn + ni * 16 + l16) * 40 + quad * 8];
#pragma unroll
        for (int mi = 0; mi < 4; ++mi)
#pragma unroll
            for (int ni = 0; ni < 4; ++ni)
                acc[mi][ni] = __builtin_amdgcn_mfma_f32_16x16x32_bf16(af[mi], bfr[ni], acc[mi][ni], 0, 0, 0);
        __syncthreads();
    }

    // ---- epilogue ----
    bf16* Co = (bf16*)Cb;
    float* Cf = (float*)Cb;
#pragma unroll
    for (int mi = 0; mi < 4; ++mi) {
#pragma unroll
        for (int ni = 0; ni < 4; ++ni) {
            int gn = n0 + wn + ni * 16 + l16;
            float bv = 0.f;
            if (BIAS == 1 && gn < N) bv = tofl(bias[gn]);
#pragma unroll
            for (int r = 0; r < 4; ++r) {
                int gm = m0 + wm + mi * 16 + quad * 4 + r;
                if (gm < M && gn < N) {
                    float v = acc[mi][ni][r] + bv;
                    if (BIAS == 2) v += tofl(bias[gm]);
                    if (ACT == 1) v = gelu_f(v);
                    if (ACT == 2) v = v > 0.f ? v + 1.f : expf(v);
                    size_t ci = coff + (size_t)gm * ldc + gn;
                    if (OUT == 0) Co[ci] = f2b(v);
                    else if (OUT == 1) Cf[ci] = v;
                    else Cf[ci] += v;
                }
            }
        }
    }
}

// ---------------- attention micro-kernels ----------------
// per-chunk partial kv/ksum: chunk c covers t in [c*621, (c+1)*621)
__global__ __launch_bounds__(256) void kv_part(
    const bf16* __restrict__ Kf, const bf16* __restrict__ V,
    float* __restrict__ kvp, float* __restrict__ ksp)
{
    int bh = blockIdx.x, c = blockIdx.y;
    int b = bh / cH, h = bh % cH;
    int tbase = c * 621, tend = tbase + 621;
    __shared__ float ks[32][64];
    __shared__ float vs[32][64];
    int tid = threadIdx.x;
    int e = tid >> 2, dg = tid & 3;
    float acc[16] = {};
    float ksacc = 0.f;
    for (int t0 = tbase; t0 < tend; t0 += 32) {
        for (int i = tid; i < 32 * 64; i += 256) {
            int tt = i >> 6, ee = i & 63;
            int t = t0 + tt;
            float kk = 0.f, vv = 0.f;
            if (t < tend) {
                size_t off = ((size_t)(b * cT + t)) * cD + h * cE;
                kk = tofl(Kf[off + ee]);
                vv = tofl(V[off + ee]);
            }
            ks[tt][ee] = kk;
            vs[tt][ee] = vv;
        }
        __syncthreads();
        for (int tt = 0; tt < 32; ++tt) {
            float kf = ks[tt][e];
            if (dg == 0) ksacc += kf;
#pragma unroll
            for (int j = 0; j < 16; ++j) acc[j] += kf * vs[tt][dg * 16 + j];
        }
        __syncthreads();
    }
    size_t base = (((size_t)c * 64 + bh) * cE + e) * cE;
#pragma unroll
    for (int j = 0; j < 16; ++j) kvp[base + dg * 16 + j] = acc[j];
    if (dg == 0) ksp[(size_t)c * 4096 + bh * cE + e] = ksacc;
}

__global__ void kv_reduce(const float* __restrict__ kvp, const float* __restrict__ ksp,
                          float* __restrict__ kvf, float* __restrict__ ksf)
{
    size_t idx = (size_t)blockIdx.x * 256 + threadIdx.x;
    if (idx < 262144) {
        float s = kvp[idx] + kvp[262144 + idx] + kvp[2 * 262144 + idx] + kvp[3 * 262144 + idx];
        kvf[idx] = s;
    } else if (idx < 262144 + 4096) {
        size_t i = idx - 262144;
        ksf[i] = ksp[i] + ksp[4096 + i] + ksp[2 * 4096 + i] + ksp[3 * 4096 + i];
    }
}

// O in-place over Q (block-local 64-wide segment)
__global__ __launch_bounds__(64) void attn_o(
    const bf16* __restrict__ Qf, const float* __restrict__ kv,
    const float* __restrict__ ksum, bf16* __restrict__ O)
{
    int g = blockIdx.x;
    int h = g % cH;
    int bt = g / cH;
    int b = bt / cT;
    int bh = b * cH + h;
    int d = threadIdx.x;
    size_t qoff = (size_t)bt * cD + h * cE;
    __shared__ float qs[64];
    float qv = tofl(Qf[qoff + d]);
    qs[d] = qv;
    float p = qv * ksum[bh * cE + d];
#pragma unroll
    for (int s = 32; s; s >>= 1) p += __shfl_down(p, s);
    float denom = __shfl(p, 0);
    __syncthreads();
    float z = 1.f / (denom + 1e-6f);
    const float* kvp = kv + (size_t)bh * cE * cE;
    float acc = 0.f;
#pragma unroll 8
    for (int e = 0; e < 64; ++e) acc += qs[e] * kvp[e * 64 + d];
    O[qoff + d] = f2b(acc * z);
}

// out = LN(a + b) * g + be   (bf16 in/out; optional dynamic second write)
template <int DUAL>
__global__ __launch_bounds__(256) void add_ln(
    const bf16* __restrict__ a, const bf16* __restrict__ b,
    const bf16* __restrict__ g, const bf16* __restrict__ be,
    bf16* __restrict__ out, void* __restrict__ dyn_out,
    const int* __restrict__ fl, size_t dyn_off)
{
    int row = blockIdx.x;
    size_t base = (size_t)row * cD;
    int t = threadIdx.x;
    float x0 = tofl(a[base + t]) + tofl(b[base + t]);
    float x1 = tofl(a[base + t + 256]) + tofl(b[base + t + 256]);
    float s1 = x0 + x1, s2 = x0 * x0 + x1 * x1;
#pragma unroll
    for (int off = 32; off; off >>= 1) { s1 += __shfl_down(s1, off); s2 += __shfl_down(s2, off); }
    __shared__ float r1[4], r2[4];
    int w = t >> 6;
    if ((t & 63) == 0) { r1[w] = s1; r2[w] = s2; }
    __syncthreads();
    float S1 = r1[0] + r1[1] + r1[2] + r1[3];
    float S2 = r2[0] + r2[1] + r2[2] + r2[3];
    float mean = S1 * (1.f / cD);
    float var = S2 * (1.f / cD) - mean * mean;
    float inv = rsqrtf(var + 1e-5f);
    float y0 = (x0 - mean) * inv * tofl(g[t]) + tofl(be[t]);
    float y1 = (x1 - mean) * inv * tofl(g[t + 256]) + tofl(be[t + 256]);
    out[base + t] = f2b(y0);
    out[base + t + 256] = f2b(y1);
    if (DUAL) {
        int bf = *fl;
        stout(dyn_out, dyn_off + base + t, y0, bf);
        stout(dyn_out, dyn_off + base + t + 256, y1, bf);
    }
}

// XT[b,o,n,d] = sum_l ttw[o,l]*t_out[b,l,n,d] + ttb[o]
__global__ void tout2_kernel(const bf16* __restrict__ tout, const bf16* __restrict__ ttw,
                             const bf16* __restrict__ ttb, bf16* __restrict__ XT)
{
    size_t idx = (size_t)blockIdx.x * 256 + threadIdx.x;
    if (idx >= SZ) return;
    int d = idx & (cD - 1);
    size_t r = idx >> 9;
    int n = (int)(r % cN);
    size_t r2 = r / cN;
    int o = (int)(r2 % cO);
    int b = (int)(r2 / cO);
    float acc = tofl(ttb[o]);
    size_t base = ((size_t)b * cT + n) * cD + d;
#pragma unroll
    for (int l = 0; l < cL; ++l)
        acc += tofl(ttw[o * cL + l]) * tofl(tout[base + (size_t)l * cN * cD]);
    XT[idx] = f2b(acc);
}

// At3[s][m][n] = adj[n,m,s]  (row stride 208, bf16)
__global__ void extract_adjT(const void* __restrict__ adj, bf16* __restrict__ At3,
                             const int* __restrict__ fl)
{
    int bf = *fl;
    int idx = blockIdx.x * 256 + threadIdx.x;
    if (idx >= cNG * cN * cN) return;
    int s = idx / (cN * cN);
    int rem = idx - s * cN * cN;
    int m = rem / cN;
    int n = rem - m * cN;
    At3[((size_t)s * cN + m) * 208 + n] = f2b(ldin(adj, (size_t)(n * cN + m) * cNG + s, bf));
}

__global__ void zerof(float* __restrict__ p, size_t n) {
    size_t i = (size_t)blockIdx.x * 256 + threadIdx.x;
    if (i < n) p[i] = 0.f;
}

// dts[b,o,n,d] = (G + gb[o,d]) * bng[o,d] + bnb[o,d]
__global__ void dts_kernel(const float* __restrict__ g, const bf16* __restrict__ gb,
                           const bf16* __restrict__ bng, const bf16* __restrict__ bnb,
                           void* __restrict__ out, const int* __restrict__ fl)
{
    int bf = *fl;
    size_t idx = (size_t)blockIdx.x * 256 + threadIdx.x;
    if (idx >= SZ) return;
    int d = idx & (cD - 1);
    size_t r = idx >> 9;
    int o = (int)((r / cN) % cO);
    int od = o * cD + d;
    float v = (g[idx] + tofl(gb[od])) * tofl(bng[od]) + tofl(bnb[od]);
    stout(out, idx, v, bf);
}

// ---------------- host helpers ----------------
static inline dim3 g2(int M, int N, int bz) { return dim3((N + 127) / 128, (M + 127) / 128, bz); }

static void run_attn(const bf16* Aq, const bf16* Akv, const bf16* wT, const bf16* bias,
                     bf16* Q, bf16* K, bf16* V, bf16* outp,
                     float* kvp, float* ksp, float* kvf, float* ksf, hipStream_t s)
{
    mgemm<true, 1, 2, 0><<<g2(cBT, cD, 1), 256, 0, s>>>(Aq,  wT,          Q, bias,          cBT, cD, cD, cD, cD, cD, 0, 0, 0, 1, 1, 0, 0);
    mgemm<true, 1, 2, 0><<<g2(cBT, cD, 1), 256, 0, s>>>(Akv, wT + DD,     K, bias + cD,     cBT, cD, cD, cD, cD, cD, 0, 0, 0, 1, 1, 0, 0);
    mgemm<true, 1, 0, 0><<<g2(cBT, cD, 1), 256, 0, s>>>(Akv, wT + 2 * DD, V, bias + 2 * cD, cBT, cD, cD, cD, cD, cD, 0, 0, 0, 1, 1, 0, 0);
    kv_part<<<dim3(64, 4), 256, 0, s>>>(K, V, kvp, ksp);
    kv_reduce<<<1041, 256, 0, s>>>(kvp, ksp, kvf, ksf);
    attn_o<<<cBT * cH, 64, 0, s>>>(Q, kvf, ksf, Q);
    mgemm<true, 1, 0, 0><<<g2(cBT, cD, 1), 256, 0, s>>>(Q, wT + 3 * DD, outp, bias + 3 * cD, cBT, cD, cD, cD, cD, cD, 0, 0, 0, 1, 1, 0, 0);
}

static void run_ffn(const bf16* inp, const bf16* w1T, const bf16* b1,
                    const bf16* w2T, const bf16* b2, bf16* mid, bf16* outp, hipStream_t s)
{
    const int MH = cBT / 2;
    for (int h = 0; h < 2; ++h) {
        const bf16* ip = inp + (size_t)h * MH * cD;
        bf16* op = outp + (size_t)h * MH * cD;
        mgemm<true, 1, 1, 0><<<g2(MH, cF, 1), 256, 0, s>>>(ip, w1T, mid, b1, MH, cF, cD, cD, cD, cF, 0, 0, 0, 1, 1, 0, 0);
        mgemm<true, 1, 0, 0><<<g2(MH, cD, 1), 256, 0, s>>>(mid, w2T, op, b2, MH, cD, cF, cF, cF, cD, 0, 0, 0, 1, 1, 0, 0);
    }
}

// ---------------- entry point ----------------
extern "C" void kernel_launch(void* const* d_in, const int* in_sizes, int n_in,
                              void* d_out, int out_size, void* d_ws, size_t ws_size,
                              hipStream_t stream)
{
    const void* x    = d_in[0];
    const void* st   = d_in[1];
    const void* adj  = d_in[3];
    const void* eqw  = d_in[4];
    const void* eqb  = d_in[5];
    const void* ew1  = d_in[6];
    const void* eb1  = d_in[7];
    const void* ew2  = d_in[8];
    const void* eb2  = d_in[9];
    const void* elng = d_in[10];
    const void* elnb = d_in[11];
    const void* dsw  = d_in[12];
    const void* dsb  = d_in[13];
    const void* dcw  = d_in[14];
    const void* dcb  = d_in[15];
    const void* dw1  = d_in[16];
    const void* db1  = d_in[17];
    const void* dw2  = d_in[18];
    const void* db2  = d_in[19];
    const void* dlng = d_in[20];
    const void* dlnb = d_in[21];
    const void* ttw  = d_in[22];
    const void* ttb  = d_in[23];
    const void* tsw  = d_in[24];
    const void* tsb  = d_in[25];
    const void* gw   = d_in[26];
    const void* gb   = d_in[27];
    const void* bng  = d_in[28];
    const void* bnb  = d_in[29];

    bf16* P = (bf16*)d_ws;
    size_t off = 0;
    auto alloc = [&](size_t n) { size_t o = off; off += (n + 127) & ~(size_t)127; return o; };

    size_t eqwT = alloc(4 * DD), dswT = alloc(4 * DD), dcwT = alloc(4 * DD);
    size_t ew1T = alloc(DD * 4 / 4 * 4);  // 512*2048 = 4*DD? no: 1,048,576
    // fix: explicit sizes
    off = eqwT;  // restart clean
    eqwT = alloc(4 * DD);
    dswT = alloc(4 * DD);
    dcwT = alloc(4 * DD);
    ew1T = alloc((size_t)cD * cF);
    size_t ew2T = alloc((size_t)cD * cF);
    size_t dw1T = alloc((size_t)cD * cF);
    size_t dw2T = alloc((size_t)cD * cF);
    size_t gwB  = alloc((size_t)cO * cD * 4608);
    size_t tswB = alloc((size_t)cN * cD);
    size_t xb   = alloc(SZ);
    size_t stb  = alloc(SZ);
    size_t eqbB = alloc(4 * cD), eb1B = alloc(cF), eb2B = alloc(cD);
    size_t elngB = alloc(2 * cD), elnbB = alloc(2 * cD);
    size_t dsbB = alloc(4 * cD), dcbB = alloc(4 * cD);
    size_t db1B = alloc(cF), db2B = alloc(cD);
    size_t dlngB = alloc(3 * cD), dlnbB = alloc(3 * cD);
    size_t ttwB = alloc(cO * cL), ttbB = alloc(cO), tsbB = alloc(cN);
    size_t gbB = alloc(cO * cD), bngB = alloc(cO * cD), bnbB = alloc(cO * cD);
    size_t at3 = alloc((size_t)cNG * cN * 208);
    size_t slots = alloc(6 * SZ);
    bf16* S[6];
    for (int i = 0; i < 6; ++i) S[i] = P + slots + (size_t)i * SZ;

    float* F0  = (float*)(P + off);
    float* kvp = F0;                    // 4*64*64*64
    float* ksp = kvp + 1048576;         // 4*4096
    float* kvf = ksp + 16384;           // 64*64*64
    float* ksf = kvf + 262144;          // 4096
    int* flag  = (int*)(ksf + 4096);

    detect_kernel<<<1, 256, 0, stream>>>(x, flag);

    // ---- converts ----
    for (int i = 0; i < 4; ++i) {
        cvt_tr<<<1024, 256, 0, stream>>>(P + eqwT + i * DD, eqw, flag, cD, cD, (size_t)i * DD);
        cvt_tr<<<1024, 256, 0, stream>>>(P + dswT + i * DD, dsw, flag, cD, cD, (size_t)i * DD);
        cvt_tr<<<1024, 256, 0, stream>>>(P + dcwT + i * DD, dcw, flag, cD, cD, (size_t)i * DD);
    }
    cvt_tr<<<4096, 256, 0, stream>>>(P + ew1T, ew1, flag, cD, cF, 0);
    cvt_tr<<<4096, 256, 0, stream>>>(P + ew2T, ew2, flag, cF, cD, 0);
    cvt_tr<<<4096, 256, 0, stream>>>(P + dw1T, dw1, flag, cD, cF, 0);
    cvt_tr<<<4096, 256, 0, stream>>>(P + dw2T, dw2, flag, cF, cD, 0);
    cvt_copy<<<27648, 256, 0, stream>>>(P + gwB, gw, flag, (size_t)cO * cD * 4608, 0);
    cvt_copy<<<104, 256, 0, stream>>>(P + tswB, tsw, flag, (size_t)cN * cD, 0);
    cvt_copy<<<(int)((SZ + 1023) / 1024), 256, 0, stream>>>(P + xb, x, flag, SZ, 0);
    cvt_copy<<<(int)((SZ + 1023) / 1024), 256, 0, stream>>>(P + stb, st, flag, SZ, 0);
    cvt_copy<<<2, 256, 0, stream>>>(P + eqbB, eqb, flag, 4 * cD, 0);
    cvt_copy<<<2, 256, 0, stream>>>(P + eb1B, eb1, flag, cF, 0);
    cvt_copy<<<1, 256, 0, stream>>>(P + eb2B, eb2, flag, cD, 0);
    cvt_copy<<<1, 256, 0, stream>>>(P + elngB, elng, flag, 2 * cD, 0);
    cvt_copy<<<1, 256, 0, stream>>>(P + elnbB, elnb, flag, 2 * cD, 0);
    cvt_copy<<<2, 256, 0, stream>>>(P + dsbB, dsb, flag, 4 * cD, 0);
    cvt_copy<<<2, 256, 0, stream>>>(P + dcbB, dcb, flag, 4 * cD, 0);
    cvt_copy<<<2, 256, 0, stream>>>(P + db1B, db1, flag, cF, 0);
    cvt_copy<<<1, 256, 0, stream>>>(P + db2B, db2, flag, cD, 0);
    cvt_copy<<<2, 256, 0, stream>>>(P + dlngB, dlng, flag, 3 * cD, 0);
    cvt_copy<<<2, 256, 0, stream>>>(P + dlnbB, dlnb, flag, 3 * cD, 0);
    cvt_copy<<<1, 256, 0, stream>>>(P + ttwB, ttw, flag, cO * cL, 0);
    cvt_copy<<<1, 256, 0, stream>>>(P + ttbB, ttb, flag, cO, 0);
    cvt_copy<<<1, 256, 0, stream>>>(P + tsbB, tsb, flag, cN, 0);
    cvt_copy<<<6, 256, 0, stream>>>(P + gbB, gb, flag, cO * cD, 0);
    cvt_copy<<<6, 256, 0, stream>>>(P + bngB, bng, flag, cO * cD, 0);
    cvt_copy<<<6, 256, 0, stream>>>(P + bnbB, bnb, flag, cO * cD, 0);

    // ===== encoder =====
    run_attn(P + xb, P + xb, P + eqwT, P + eqbB, S[0], S[1], S[2], S[3], kvp, ksp, kvf, ksf, stream);
    add_ln<0><<<cBT, 256, 0, stream>>>(P + xb, S[3], P + elngB, P + elnbB, S[4], nullptr, flag, 0);   // y
    run_ffn(S[4], P + ew1T, P + eb1B, P + ew2T, P + eb2B, S[0], S[2], stream);
    add_ln<0><<<cBT, 256, 0, stream>>>(S[4], S[2], P + elngB + cD, P + elnbB + cD, S[5], nullptr, flag, 0);  // t_out

    // ===== decoder self-attn =====
    run_attn(P + stb, P + stb, P + dswT, P + dsbB, S[0], S[1], S[2], S[3], kvp, ksp, kvf, ksf, stream);
    add_ln<0><<<cBT, 256, 0, stream>>>(P + stb, S[3], P + dlngB, P + dlnbB, S[4], nullptr, flag, 0);  // q1

    // ===== decoder cross-attn (Q from q1, KV from t_out) =====
    run_attn(S[4], S[5], P + dcwT, P + dcbB, S[0], S[1], S[2], S[3], kvp, ksp, kvf, ksf, stream);
    add_ln<0><<<cBT, 256, 0, stream>>>(S[4], S[3], P + dlngB + cD, P + dlnbB + cD, S[4], nullptr, flag, 0);  // q2 (in-place)

    // ===== decoder FFN + s_out =====
    run_ffn(S[4], P + dw1T, P + db1B, P + dw2T, P + db2B, S[0], S[2], stream);
    add_ln<1><<<cBT, 256, 0, stream>>>(S[4], S[2], P + dlngB + 2 * cD, P + dlnbB + 2 * cD, S[3], d_out, flag, SZ);

    // ===== temporal projection X_T -> S0 =====
    tout2_kernel<<<(int)(SZ / 256), 256, 0, stream>>>(S[5], P + ttwB, P + ttbB, S[0]);

    // ===== adaptive adjacency AadT[bz][m][n] (ldc=208) -> S1 =====
    mgemm<true, 2, 0, 0><<<g2(cN, cN, cB * cO), 256, 0, stream>>>(
        P + tswB, S[3], S[1], P + tsbB, cN, cN, cD, cD, cD, 208,
        0, (long)cN * cD, (long)cN * 208, 1, 0, 0, 0);

    extract_adjT<<<(cNG * cN * cN + 255) / 256, 256, 0, stream>>>(adj, P + at3, flag);

    // ===== graph diffusion + GCN =====
    float* G = (float*)S[4];           // S4+S5 = SZ floats
    zerof<<<(int)((SZ + 255) / 256), 256, 0, stream>>>(G, SZ);

    auto accum = [&](const bf16* Feat, int f) {
        mgemm<true, 0, 0, 2><<<g2(cN, cD, cB * cO), 256, 0, stream>>>(
            Feat, P + gwB, G, nullptr, cN, cD, cD, cD, 4608, cD,
            (long)cN * cD, (long)cD * 4608, (long)cN * cD, 0, cO, 0, (long)f * cD);
    };
    auto featmul = [&](const bf16* A, long sA, int modA, long aoff0, const bf16* Fin, bf16* Fout) {
        mgemm<false, 0, 0, 0><<<g2(cN, cD, cB * cO), 256, 0, stream>>>(
            A, Fin, Fout, nullptr, cN, cD, cN, 208, cD, cD,
            sA, (long)cN * cD, (long)cN * cD, modA, 0, aoff0, 0);
    };

    accum(S[0], 0);
    for (int s = 0; s < cNG; ++s) {
        featmul(P + at3, 0, 1, (long)s * cN * 208, S[0], S[3]);
        accum(S[3], 2 * s + 1);
        featmul(P + at3, 0, 1, (long)s * cN * 208, S[3], S[2]);
        accum(S[2], 2 * s + 2);
    }
    featmul(S[1], (long)cN * 208, 0, 0, S[0], S[3]);
    accum(S[3], 7);
    featmul(S[1], (long)cN * 208, 0, 0, S[3], S[2]);
    accum(S[2], 8);

    // ===== epilogue =====
    dts_kernel<<<(int)((SZ + 255) / 256), 256, 0, stream>>>(G, P + gbB, P + bngB, P + bnbB, d_out, flag);
}